// Round 6
// baseline (5955.753 us; speedup 1.0000x reference)
//
#include <hip/hip_runtime.h>

typedef __bf16 bf16x8 __attribute__((ext_vector_type(8)));
typedef float f32x4 __attribute__((ext_vector_type(4)));
typedef unsigned short u16;
typedef unsigned long long u64;

#define NSTEP 512
#define RELIDX 8224
#define WLDS_BYTES (32 * 32 * 36 * 2)   // 73728

#define AL(p)   __hip_atomic_load((p), __ATOMIC_RELAXED, __HIP_MEMORY_SCOPE_AGENT)
#define AS(p,v) __hip_atomic_store((p), (v), __ATOMIC_RELAXED, __HIP_MEMORY_SCOPE_AGENT)

__device__ __forceinline__ u16 f2bf(float f) {
  union { float f; unsigned u; } x; x.f = f;
  return (u16)((x.u + 0x7fffu + ((x.u >> 16) & 1u)) >> 16);
}

// zero h buffer 0 + barrier flags (runs every call -> deterministic replays)
__global__ void prep_kernel(u16* __restrict__ h0, int* __restrict__ bar) {
  int i = blockIdx.x * blockDim.x + threadIdx.x;
  if (i < 65536) h0[i] = 0;
  if (i < 8256) bar[i] = 0;
}

// A1[t*64+b][512] bf16 embedding gather
__global__ void gather_kernel(const int* __restrict__ sent, const float* __restrict__ emb,
                              u16* __restrict__ A1) {
  int row = blockIdx.x * 4 + (threadIdx.x >> 6);   // t*64+b
  int lane = threadIdx.x & 63;
  int t = row >> 6, b = row & 63;
  int idx = sent[b * 512 + t];
  const float* src = emb + (size_t)idx * 512 + lane * 8;
  u16* dst = A1 + (size_t)row * 512 + lane * 8;
  #pragma unroll
  for (int k = 0; k < 8; ++k) dst[k] = f2bf(src[k]);
}

// 256 WGs = 128 col-groups x 2 batch-groups, 256 thr each.
// WG (j,bg): h cols [j*8, j*8+8), batch rows [bg*32, bg*32+32).
// Wave w: bt=w&1 (batch 16-row tile), ct=w>>1 (4-col tile) -> jj=j*2+ct acts
// exactly like r5's per-wave col-group. Gate packing rb16 = g*4+nn = lr.
// Weights: x + h-first-half in 72KB padded dynamic LDS; h-second-half in VGPRs.
// h exchanged via agent-scope relaxed atomics; padded-flag barrier, no fences.
__global__ void __launch_bounds__(256, 2)
lstm_kernel(const u16* __restrict__ A1,
            const float* __restrict__ wih, const float* __restrict__ whh,
            const float* __restrict__ bih, const float* __restrict__ bhh,
            u16* __restrict__ h3, float* __restrict__ out, int* __restrict__ bar) {
  extern __shared__ u16 wlds[];             // [32 kk][32 rb][36 pad]
  __shared__ alignas(8) u16 hx[4][16][4];   // per-wave h-store packing bounce

  const int bx  = blockIdx.x;
  const int j   = bx >> 1;             // col-group 0..127
  const int bg  = bx & 1;              // batch-group 0..1
  const int tid = threadIdx.x;
  const int w   = tid >> 6;
  const int bt  = w & 1, ct = w >> 1;
  const int l   = tid & 63;
  const int lr  = l & 15, lk = l >> 4;
  const int g   = lr >> 2, nn = lr & 3;
  const int jj  = j * 2 + ct;          // effective 4-col group 0..255
  const int wrow = g * 1024 + jj * 4 + nn;

  // ---- stage LDS weights (x: kk 0..15, h-k [0,512): kk 16..31) ----
  for (int task = tid; task < 4096; task += 256) {
    int kk = task >> 7;                 // 0..31
    int rem = task & 127;
    int rb = rem >> 2, q = rem & 3;     // rb 0..31 = ct*16 + g*4 + nn
    int row = ((rb & 15) >> 2) * 1024 + j * 8 + (rb >> 4) * 4 + (rb & 3);
    const float* src = (kk < 16) ? (wih + (size_t)row * 512 + kk * 32 + q * 8)
                                 : (whh + (size_t)row * 1024 + (kk - 16) * 32 + q * 8);
    u16* dst = wlds + (size_t)(kk * 32 + rb) * 36 + q * 8;
    #pragma unroll
    for (int e = 0; e < 8; ++e) dst[e] = f2bf(src[e]);
  }
  // ---- VGPR weights: h-k [512,1024) (64 VGPRs) ----
  bf16x8 wv[16];
  {
    const float* ph = whh + (size_t)wrow * 1024 + 512 + lk * 8;
    #pragma unroll
    for (int kk = 0; kk < 16; ++kk) {
      union { bf16x8 v; u16 s[8]; } u;
      #pragma unroll
      for (int e = 0; e < 8; ++e) u.s[e] = f2bf(ph[kk * 32 + e]);
      wv[kk] = u.v;
    }
  }
  __syncthreads();

  const float bias = bih[wrow] + bhh[wrow];
  const float sca = (g == 2) ? 2.f : 1.f;   // tanh-as-sigmoid scaling
  const float bd  = (g == 2) ? -1.f : 0.f;
  const int arow = bg * 32 + bt * 16 + lr;  // batch row for A fragments
  const u16* bxp = wlds + (size_t)(ct * 16 + lr) * 36 + lk * 8;  // + kk*1152

  float cst[4] = {0.f, 0.f, 0.f, 0.f};

  union AF { bf16x8 v; u64 q[2]; };

#define LD8(BUF, CH)                                                        \
  { _Pragma("unroll")                                                       \
    for (int r = 0; r < 8; ++r) {                                           \
      u64* p = (u64*)(hp + (CH) * 256 + r * 32);                            \
      BUF[r].q[0] = AL(p); BUF[r].q[1] = AL(p + 1);                         \
    } }
#define MM8L(BUF, KK0)                                                      \
  { _Pragma("unroll")                                                       \
    for (int r = 0; r < 8; ++r) {                                           \
      bf16x8 b = *(const bf16x8*)(bxp + (size_t)((KK0) + r) * 1152);        \
      ach = __builtin_amdgcn_mfma_f32_16x16x32_bf16(BUF[r].v, b, ach, 0, 0, 0); \
    } }
#define MM8V(BUF, V0)                                                       \
  { _Pragma("unroll")                                                       \
    for (int r = 0; r < 8; ++r)                                             \
      ach = __builtin_amdgcn_mfma_f32_16x16x32_bf16(BUF[r].v, wv[(V0) + r], ach, 0, 0, 0); }

  // A1 prefetch + x-projection for t=0
  bf16x8 ax[16];
  f32x4 acx = { bias, bias, bias, bias };
  {
    const u16* apre = A1 + (size_t)arow * 512 + lk * 8;
    #pragma unroll
    for (int kk = 0; kk < 16; ++kk) ax[kk] = *(const bf16x8*)(apre + kk * 32);
    #pragma unroll
    for (int kk = 0; kk < 16; ++kk) {
      bf16x8 b = *(const bf16x8*)(bxp + (size_t)kk * 1152);
      acx = __builtin_amdgcn_mfma_f32_16x16x32_bf16(ax[kk], b, acx, 0, 0, 0);
    }
  }

  #pragma unroll 1
  for (int t = 0; t < NSTEP; ++t) {
    AF ha[8], hb[8];
    const u16* hp = h3 + (size_t)(t % 3) * 65536 + (size_t)arow * 1024 + lk * 8;
    f32x4 ach = { 0.f, 0.f, 0.f, 0.f };
    // h-projection: double-buffered 8-fragment chunks
    LD8(ha, 0); LD8(hb, 1);
    MM8L(ha, 16);            // h-k [0,256)   from LDS
    LD8(ha, 2);
    MM8L(hb, 24);            // h-k [256,512) from LDS
    LD8(hb, 3);
    MM8V(ha, 0);             // h-k [512,768) from VGPR weights
    MM8V(hb, 8);             // h-k [768,1024)

    // activations + state update; lanes lr<4 own (rows lk*4+r, col lr)
    float hv4[4], cn4[4];
    #pragma unroll
    for (int r = 0; r < 4; ++r) {
      float xv = acx[r] + ach[r];
      float act = sca / (1.f + __expf(-sca * xv)) + bd;  // sigmoid / tanh
      float gg = __shfl_xor(act, 8);
      float ff = __shfl_xor(act, 4);
      float oo = __shfl_xor(act, 12);
      float cn = ff * cst[r] + act * gg;   // act = i at lanes lr<4
      cst[r] = cn;
      float tc = 2.f / (1.f + __expf(-2.f * cn)) - 1.f;
      hv4[r] = oo * tc;
      cn4[r] = cn;
    }

    if (t == NSTEP - 1) {
      if (lr < 4) {
        #pragma unroll
        for (int r = 0; r < 4; ++r) {
          int R = bg * 32 + bt * 16 + lk * 4 + r;
          out[(size_t)R * 1024 + jj * 4 + lr]          = hv4[r];
          out[65536 + (size_t)R * 1024 + jj * 4 + lr]  = hv4[r];
          out[131072 + (size_t)R * 1024 + jj * 4 + lr] = cn4[r];
        }
      }
    } else {
      // pack h tile 16x4 per wave -> one 8B agent-scope store per row
      if (lr < 4) {
        #pragma unroll
        for (int r = 0; r < 4; ++r) hx[w][lk * 4 + r][lr] = f2bf(hv4[r]);
      }
      __syncthreads();
      if (l < 16) {
        u64 pk = *(const u64*)(&hx[w][l][0]);
        u16* hw = h3 + (size_t)((t + 1) % 3) * 65536
                     + (size_t)(bg * 32 + bt * 16 + l) * 1024 + jj * 4;
        AS((u64*)hw, pk);
      }
      asm volatile("s_waitcnt vmcnt(0)" ::: "memory");   // h stores at coherence point
      __syncthreads();
      const int t1 = t + 1;
      if (tid == 0) AS(&bar[bx * 32], t1);
      // A1 prefetch + x-projection for t1: fills the barrier-wait window
      {
        const u16* apre = A1 + ((size_t)t1 * 64 + arow) * 512 + lk * 8;
        #pragma unroll
        for (int kk = 0; kk < 16; ++kk) ax[kk] = *(const bf16x8*)(apre + kk * 32);
        f32x4 an = { bias, bias, bias, bias };
        #pragma unroll
        for (int kk = 0; kk < 16; ++kk) {
          bf16x8 b = *(const bf16x8*)(bxp + (size_t)kk * 1152);
          an = __builtin_amdgcn_mfma_f32_16x16x32_bf16(ax[kk], b, an, 0, 0, 0);
        }
        acx = an;
      }
      if (bx == 0) {     // WG0: 256 threads poll 256 flags in parallel
        while (AL(&bar[tid * 32]) < t1) __builtin_amdgcn_s_sleep(1);
        __syncthreads();
        if (tid == 0) AS(&bar[RELIDX], t1);
      } else {
        if (tid == 0) {
          while (AL(&bar[RELIDX]) < t1) __builtin_amdgcn_s_sleep(1);
        }
      }
      __syncthreads();
    }
  }
#undef LD8
#undef MM8L
#undef MM8V
}

extern "C" void kernel_launch(void* const* d_in, const int* in_sizes, int n_in,
                              void* d_out, int out_size, void* d_ws, size_t ws_size,
                              hipStream_t stream) {
  const int*   sent = (const int*)d_in[0];
  const float* emb  = (const float*)d_in[1];
  const float* w_ih = (const float*)d_in[2];
  const float* w_hh = (const float*)d_in[3];
  const float* b_ih = (const float*)d_in[4];
  const float* b_hh = (const float*)d_in[5];
  float* out = (float*)d_out;

  char* ws = (char*)d_ws;
  u16* A1 = (u16*)ws;                            // 32 MiB
  u16* h3 = (u16*)(ws + 33554432);               // 3 x 128 KiB triple-buffered h
  int* bar = (int*)(ws + 33554432 + 393216);     // padded flags + release line

  prep_kernel<<<256, 256, 0, stream>>>(h3, bar);
  gather_kernel<<<8192, 256, 0, stream>>>(sent, emb, A1);

  (void)hipFuncSetAttribute((const void*)lstm_kernel,
                            hipFuncAttributeMaxDynamicSharedMemorySize, WLDS_BYTES);

  void* args[] = { (void*)&A1, (void*)&w_ih, (void*)&w_hh,
                   (void*)&b_ih, (void*)&b_hh, (void*)&h3, (void*)&out, (void*)&bar };
  hipError_t err = hipLaunchCooperativeKernel((void*)lstm_kernel, dim3(256), dim3(256),
                                              args, WLDS_BYTES, stream);
  if (err != hipSuccess) {
    // custom barrier (no cg grid.sync): plain launch is fine when all 256 WGs
    // are co-resident, which the 2-blocks/CU resource envelope guarantees
    lstm_kernel<<<dim3(256), dim3(256), WLDS_BYTES, stream>>>(A1, w_ih, w_hh,
                                                              b_ih, b_hh, h3, out, bar);
  }
}

// Round 7
// 5849.422 us; speedup vs baseline: 1.0182x; 1.0182x over previous
//
#include <hip/hip_runtime.h>

typedef __bf16 bf16x8 __attribute__((ext_vector_type(8)));
typedef float f32x4 __attribute__((ext_vector_type(4)));
typedef unsigned short u16;
typedef unsigned long long u64;

#define NSTEP 512
#define RELBASE 8192   // release slots start (ints); flags at [wg*32], rel at [RELBASE+wg*32]

#define AL(p)   __hip_atomic_load((p), __ATOMIC_RELAXED, __HIP_MEMORY_SCOPE_AGENT)
#define AS(p,v) __hip_atomic_store((p), (v), __ATOMIC_RELAXED, __HIP_MEMORY_SCOPE_AGENT)

__device__ __forceinline__ u16 f2bf(float f) {
  union { float f; unsigned u; } x; x.f = f;
  return (u16)((x.u + 0x7fffu + ((x.u >> 16) & 1u)) >> 16);
}

// zero h buffer 0 + barrier state (runs every call -> deterministic replays)
__global__ void prep_kernel(u16* __restrict__ h0, int* __restrict__ bar) {
  int i = blockIdx.x * blockDim.x + threadIdx.x;
  if (i < 65536) h0[i] = 0;
  if (i < 16416) bar[i] = 0;
}

// A1[t*64+b][512] bf16 embedding gather
__global__ void gather_kernel(const int* __restrict__ sent, const float* __restrict__ emb,
                              u16* __restrict__ A1) {
  int row = blockIdx.x * 4 + (threadIdx.x >> 6);   // t*64+b
  int lane = threadIdx.x & 63;
  int t = row >> 6, b = row & 63;
  int idx = sent[b * 512 + t];
  const float* src = emb + (size_t)idx * 512 + lane * 8;
  u16* dst = A1 + (size_t)row * 512 + lane * 8;
  #pragma unroll
  for (int k = 0; k < 8; ++k) dst[k] = f2bf(src[k]);
}

// 256 WGs x 256 thr. WG j owns h cols [j*4,j*4+4), 4 gates packed (rb = g*4+nn = lr).
// Weights in padded LDS; h exchanged via agent-scope relaxed atomics.
// Barrier: private arrival flag per WG (read by WG0 thread j) + private release
// slot per WG (written by WG0 thread j, read by WG j's tid0). Zero line sharing.
__global__ void __launch_bounds__(256, 2)
lstm_kernel(const u16* __restrict__ A1,
            const float* __restrict__ wih, const float* __restrict__ whh,
            const float* __restrict__ bih, const float* __restrict__ bhh,
            u16* __restrict__ h3, float* __restrict__ out, int* __restrict__ bar) {
  __shared__ u16 wlds[48 * 16 * 36];        // 55296 B, stride-36 pad
  __shared__ alignas(8) u16 hx[4][16][4];   // per-wave h-store packing bounce

  const int j   = blockIdx.x;
  const int tid = threadIdx.x;
  const int w   = tid >> 6;            // wave = batch tile 0..3
  const int l   = tid & 63;
  const int lr  = l & 15, lk = l >> 4;
  const int g   = lr >> 2, nn = lr & 3;
  const int wrow = g * 1024 + j * 4 + nn;

  // ---- stage ALL weights fp32->bf16 into padded LDS (once) ----
  for (int task = tid; task < 3072; task += 256) {
    int kk = task >> 6;                 // K chunk of 32 (0..47)
    int rem = task & 63;
    int rb = rem >> 2, q = rem & 3;
    int row = (rb >> 2) * 1024 + j * 4 + (rb & 3);
    const float* src = (kk < 16) ? (wih + (size_t)row * 512 + kk * 32 + q * 8)
                                 : (whh + (size_t)row * 1024 + (kk - 16) * 32 + q * 8);
    u16* dst = wlds + (kk * 16 + rb) * 36 + q * 8;
    #pragma unroll
    for (int e = 0; e < 8; ++e) dst[e] = f2bf(src[e]);
  }
  __syncthreads();

  const float bias = bih[wrow] + bhh[wrow];
  const float sca = (g == 2) ? 2.f : 1.f;   // tanh-as-sigmoid scaling
  const float bd  = (g == 2) ? -1.f : 0.f;
  const int arow = w * 16 + lr;             // batch row for A fragments
  const u16* bx = wlds + lr * 36 + lk * 8;  // + kk*576 per K chunk

  float cst[4] = {0.f, 0.f, 0.f, 0.f};

  // prefetch A1 fragments for t=0
  bf16x8 ax[16];
  {
    const u16* apre = A1 + (size_t)arow * 512 + lk * 8;
    #pragma unroll
    for (int kk = 0; kk < 16; ++kk) ax[kk] = *(const bf16x8*)(apre + kk * 32);
  }

  union AF { bf16x8 v; u64 q[2]; };

#define LD8(BUF, CH)                                                        \
  { _Pragma("unroll")                                                       \
    for (int r = 0; r < 8; ++r) {                                           \
      u64* p = (u64*)(hp + (CH) * 256 + r * 32);                            \
      BUF[r].q[0] = AL(p); BUF[r].q[1] = AL(p + 1);                         \
    } }
#define MM8(BUF, W0)                                                        \
  { _Pragma("unroll")                                                       \
    for (int r = 0; r < 8; ++r) {                                           \
      bf16x8 b = *(const bf16x8*)(bx + ((W0) + r) * 576);                   \
      acc = __builtin_amdgcn_mfma_f32_16x16x32_bf16(BUF[r].v, b, acc, 0, 0, 0); \
    } }

  #pragma unroll 1
  for (int t = 0; t < NSTEP; ++t) {
    AF ha[8], hb[8];
    const u16* hp = h3 + (size_t)(t % 3) * 65536 + (size_t)arow * 1024 + lk * 8;
    LD8(ha, 0);                          // h chunk 0 in flight
    // x-projection from prefetched ax (overlaps h-load latency)
    f32x4 acc = { bias, bias, bias, bias };
    #pragma unroll
    for (int kk = 0; kk < 16; ++kk) {
      bf16x8 b = *(const bf16x8*)(bx + kk * 576);
      acc = __builtin_amdgcn_mfma_f32_16x16x32_bf16(ax[kk], b, acc, 0, 0, 0);
    }
    // h-projection: double-buffered 8-fragment chunks (static names, no scratch)
    LD8(hb, 1); MM8(ha, 16);
    LD8(ha, 2); MM8(hb, 24);
    LD8(hb, 3); MM8(ha, 32);
    MM8(hb, 40);

    // activations + state update; lanes lr<4 own (rows lk*4+r, col lr)
    float hv4[4], cn4[4];
    #pragma unroll
    for (int r = 0; r < 4; ++r) {
      float xv = acc[r];
      float act = sca / (1.f + __expf(-sca * xv)) + bd;  // sigmoid / tanh
      float gg = __shfl_xor(act, 8);
      float ff = __shfl_xor(act, 4);
      float oo = __shfl_xor(act, 12);
      float cn = ff * cst[r] + act * gg;   // act = i at lanes lr<4
      cst[r] = cn;
      float tc = 2.f / (1.f + __expf(-2.f * cn)) - 1.f;
      hv4[r] = oo * tc;
      cn4[r] = cn;
    }

    if (t == NSTEP - 1) {
      if (lr < 4) {
        #pragma unroll
        for (int r = 0; r < 4; ++r) {
          int R = w * 16 + lk * 4 + r;
          out[(size_t)R * 1024 + j * 4 + lr]          = hv4[r];
          out[65536 + (size_t)R * 1024 + j * 4 + lr]  = hv4[r];
          out[131072 + (size_t)R * 1024 + j * 4 + lr] = cn4[r];
        }
      }
    } else {
      // pack h tile 64x4 -> one 8B agent-scope store per row
      if (lr < 4) {
        #pragma unroll
        for (int r = 0; r < 4; ++r) hx[w][lk * 4 + r][lr] = f2bf(hv4[r]);
      }
      __syncthreads();
      if (l < 16) {
        u64 pk = *(const u64*)(&hx[w][l][0]);
        u16* hw = h3 + (size_t)((t + 1) % 3) * 65536 + (size_t)(w * 16 + l) * 1024 + j * 4;
        AS((u64*)hw, pk);
      }
      // h stores reach coherence point before the arrival flag
      asm volatile("s_waitcnt vmcnt(0)" ::: "memory");
      __syncthreads();
      const int t1 = t + 1;
      if (tid == 0) AS(&bar[j * 32], t1);
      // prefetch A1 for t+1; latency hides under the barrier window
      {
        const u16* apre = A1 + ((size_t)t1 * 64 + arow) * 512 + lk * 8;
        #pragma unroll
        for (int kk = 0; kk < 16; ++kk) ax[kk] = *(const bf16x8*)(apre + kk * 32);
      }
      if (j == 0) {
        // WG0: thread i polls WG i's arrival flag, then releases WG i's private slot
        while (AL(&bar[tid * 32]) < t1) __builtin_amdgcn_s_sleep(1);
        __syncthreads();
        AS(&bar[RELBASE + tid * 32], t1);
      } else {
        if (tid == 0) {
          while (AL(&bar[RELBASE + j * 32]) < t1) { /* tight spin, private line */ }
        }
      }
      __syncthreads();
    }
  }
#undef LD8
#undef MM8
}

extern "C" void kernel_launch(void* const* d_in, const int* in_sizes, int n_in,
                              void* d_out, int out_size, void* d_ws, size_t ws_size,
                              hipStream_t stream) {
  const int*   sent = (const int*)d_in[0];
  const float* emb  = (const float*)d_in[1];
  const float* w_ih = (const float*)d_in[2];
  const float* w_hh = (const float*)d_in[3];
  const float* b_ih = (const float*)d_in[4];
  const float* b_hh = (const float*)d_in[5];
  float* out = (float*)d_out;

  char* ws = (char*)d_ws;
  u16* A1 = (u16*)ws;                            // 32 MiB
  u16* h3 = (u16*)(ws + 33554432);               // 3 x 128 KiB triple-buffered h
  int* bar = (int*)(ws + 33554432 + 393216);     // arrival flags + private release slots

  prep_kernel<<<256, 256, 0, stream>>>(h3, bar);
  gather_kernel<<<8192, 256, 0, stream>>>(sent, emb, A1);

  void* args[] = { (void*)&A1, (void*)&w_ih, (void*)&w_hh,
                   (void*)&b_ih, (void*)&b_hh, (void*)&h3, (void*)&out, (void*)&bar };
  hipError_t err = hipLaunchCooperativeKernel((void*)lstm_kernel, dim3(256), dim3(256),
                                              args, 0, stream);
  if (err != hipSuccess) {
    // custom barrier (no cg grid.sync): plain launch is fine when all 256 WGs
    // are co-resident, which the 2-blocks/CU resource envelope guarantees
    lstm_kernel<<<dim3(256), dim3(256), 0, stream>>>(A1, w_ih, w_hh, b_ih, b_hh,
                                                     h3, out, bar);
  }
}

// Round 8
// 5434.721 us; speedup vs baseline: 1.0959x; 1.0763x over previous
//
#include <hip/hip_runtime.h>

typedef __bf16 bf16x8 __attribute__((ext_vector_type(8)));
typedef float f32x4 __attribute__((ext_vector_type(4)));
typedef unsigned short u16;
typedef unsigned long long u64;

#define NSTEP 512

#define AL(p)   __hip_atomic_load((p), __ATOMIC_RELAXED, __HIP_MEMORY_SCOPE_AGENT)
#define AS(p,v) __hip_atomic_store((p), (v), __ATOMIC_RELAXED, __HIP_MEMORY_SCOPE_AGENT)

__device__ __forceinline__ u16 f2bf(float f) {
  union { float f; unsigned u; } x; x.f = f;
  return (u16)((x.u + 0x7fffu + ((x.u >> 16) & 1u)) >> 16);
}

// zero h buffer 0 + barrier flags (runs every call -> deterministic replays)
__global__ void prep_kernel(u16* __restrict__ h0, int* __restrict__ bar) {
  int i = blockIdx.x * blockDim.x + threadIdx.x;
  if (i < 65536) h0[i] = 0;
  if (i < 16416) bar[i] = 0;
}

// A1[t*64+b][512] bf16 embedding gather
__global__ void gather_kernel(const int* __restrict__ sent, const float* __restrict__ emb,
                              u16* __restrict__ A1) {
  int row = blockIdx.x * 4 + (threadIdx.x >> 6);   // t*64+b
  int lane = threadIdx.x & 63;
  int t = row >> 6, b = row & 63;
  int idx = sent[b * 512 + t];
  const float* src = emb + (size_t)idx * 512 + lane * 8;
  u16* dst = A1 + (size_t)row * 512 + lane * 8;
  #pragma unroll
  for (int k = 0; k < 8; ++k) dst[k] = f2bf(src[k]);
}

// 256 WGs x 256 thr. WG j owns h cols [j*4,j*4+4), 4 gates packed (rb = g*4+nn = lr).
// Weights in padded LDS; h exchanged via agent-scope relaxed atomics.
// Barrier: per-WG monotonic epoch flag (own 128B line). Each consumer WG's 256
// threads poll all 256 producer flags directly (one each) -> syncthreads.
// Removes the WG0 detect+release 2-hop of r5/r7.
__global__ void __launch_bounds__(256, 2)
lstm_kernel(const u16* __restrict__ A1,
            const float* __restrict__ wih, const float* __restrict__ whh,
            const float* __restrict__ bih, const float* __restrict__ bhh,
            u16* __restrict__ h3, float* __restrict__ out, int* __restrict__ bar) {
  __shared__ u16 wlds[48 * 16 * 36];        // 55296 B, stride-36 pad
  __shared__ alignas(8) u16 hx[4][16][4];   // per-wave h-store packing bounce

  const int j   = blockIdx.x;
  const int tid = threadIdx.x;
  const int w   = tid >> 6;            // wave = batch tile 0..3
  const int l   = tid & 63;
  const int lr  = l & 15, lk = l >> 4;
  const int g   = lr >> 2, nn = lr & 3;
  const int wrow = g * 1024 + j * 4 + nn;

  // ---- stage ALL weights fp32->bf16 into padded LDS (once) ----
  for (int task = tid; task < 3072; task += 256) {
    int kk = task >> 6;                 // K chunk of 32 (0..47)
    int rem = task & 63;
    int rb = rem >> 2, q = rem & 3;
    int row = (rb >> 2) * 1024 + j * 4 + (rb & 3);
    const float* src = (kk < 16) ? (wih + (size_t)row * 512 + kk * 32 + q * 8)
                                 : (whh + (size_t)row * 1024 + (kk - 16) * 32 + q * 8);
    u16* dst = wlds + (kk * 16 + rb) * 36 + q * 8;
    #pragma unroll
    for (int e = 0; e < 8; ++e) dst[e] = f2bf(src[e]);
  }
  __syncthreads();

  const float bias = bih[wrow] + bhh[wrow];
  const float sca = (g == 2) ? 2.f : 1.f;   // tanh-as-sigmoid scaling
  const float bd  = (g == 2) ? -1.f : 0.f;
  const int arow = w * 16 + lr;             // batch row for A fragments
  const u16* bx = wlds + lr * 36 + lk * 8;  // + kk*576 per K chunk

  float cst[4] = {0.f, 0.f, 0.f, 0.f};

  // prefetch A1 fragments for t=0
  bf16x8 ax[16];
  {
    const u16* apre = A1 + (size_t)arow * 512 + lk * 8;
    #pragma unroll
    for (int kk = 0; kk < 16; ++kk) ax[kk] = *(const bf16x8*)(apre + kk * 32);
  }

  union AF { bf16x8 v; u64 q[2]; };

#define LD8(BUF, CH)                                                        \
  { _Pragma("unroll")                                                       \
    for (int r = 0; r < 8; ++r) {                                           \
      u64* p = (u64*)(hp + (CH) * 256 + r * 32);                            \
      BUF[r].q[0] = AL(p); BUF[r].q[1] = AL(p + 1);                         \
    } }
#define MM8(BUF, W0)                                                        \
  { _Pragma("unroll")                                                       \
    for (int r = 0; r < 8; ++r) {                                           \
      bf16x8 b = *(const bf16x8*)(bx + ((W0) + r) * 576);                   \
      acc = __builtin_amdgcn_mfma_f32_16x16x32_bf16(BUF[r].v, b, acc, 0, 0, 0); \
    } }

  #pragma unroll 1
  for (int t = 0; t < NSTEP; ++t) {
    AF ha[8], hb[8];
    const u16* hp = h3 + (size_t)(t % 3) * 65536 + (size_t)arow * 1024 + lk * 8;
    LD8(ha, 0);                          // 32 h-loads in flight through x-proj
    LD8(hb, 1);
    // x-projection from prefetched ax (overlaps h-load latency)
    f32x4 acc = { bias, bias, bias, bias };
    #pragma unroll
    for (int kk = 0; kk < 16; ++kk) {
      bf16x8 b = *(const bf16x8*)(bx + kk * 576);
      acc = __builtin_amdgcn_mfma_f32_16x16x32_bf16(ax[kk], b, acc, 0, 0, 0);
    }
    // h-projection: double-buffered 8-fragment chunks (static names, no scratch)
    MM8(ha, 16);
    LD8(ha, 2); MM8(hb, 24);
    LD8(hb, 3); MM8(ha, 32);
    MM8(hb, 40);

    // activations + state update; lanes lr<4 own (rows lk*4+r, col lr)
    float hv4[4], cn4[4];
    #pragma unroll
    for (int r = 0; r < 4; ++r) {
      float xv = acc[r];
      float act = sca / (1.f + __expf(-sca * xv)) + bd;  // sigmoid / tanh
      float gg = __shfl_xor(act, 8);
      float ff = __shfl_xor(act, 4);
      float oo = __shfl_xor(act, 12);
      float cn = ff * cst[r] + act * gg;   // act = i at lanes lr<4
      cst[r] = cn;
      float tc = 2.f / (1.f + __expf(-2.f * cn)) - 1.f;
      hv4[r] = oo * tc;
      cn4[r] = cn;
    }

    if (t == NSTEP - 1) {
      if (lr < 4) {
        #pragma unroll
        for (int r = 0; r < 4; ++r) {
          int R = w * 16 + lk * 4 + r;
          out[(size_t)R * 1024 + j * 4 + lr]          = hv4[r];
          out[65536 + (size_t)R * 1024 + j * 4 + lr]  = hv4[r];
          out[131072 + (size_t)R * 1024 + j * 4 + lr] = cn4[r];
        }
      }
    } else {
      // pack h tile 64x4 -> one 8B agent-scope store per row
      if (lr < 4) {
        #pragma unroll
        for (int r = 0; r < 4; ++r) hx[w][lk * 4 + r][lr] = f2bf(hv4[r]);
      }
      __syncthreads();
      if (l < 16) {
        u64 pk = *(const u64*)(&hx[w][l][0]);
        u16* hw = h3 + (size_t)((t + 1) % 3) * 65536 + (size_t)(w * 16 + l) * 1024 + j * 4;
        AS((u64*)hw, pk);
      }
      // h stores reach coherence point before the arrival flag
      asm volatile("s_waitcnt vmcnt(0)" ::: "memory");
      __syncthreads();
      const int t1 = t + 1;
      if (tid == 0) AS(&bar[j * 32], t1);          // publish epoch (monotonic)
      // prefetch A1 for t+1; latency hides under the flag-wait window
      {
        const u16* apre = A1 + ((size_t)t1 * 64 + arow) * 512 + lk * 8;
        #pragma unroll
        for (int kk = 0; kk < 16; ++kk) ax[kk] = *(const bf16x8*)(apre + kk * 32);
      }
      // direct all-to-all wait: thread tid polls producer tid's epoch flag
      while (AL(&bar[tid * 32]) < t1) __builtin_amdgcn_s_sleep(1);
      __syncthreads();
    }
  }
#undef LD8
#undef MM8
}

extern "C" void kernel_launch(void* const* d_in, const int* in_sizes, int n_in,
                              void* d_out, int out_size, void* d_ws, size_t ws_size,
                              hipStream_t stream) {
  const int*   sent = (const int*)d_in[0];
  const float* emb  = (const float*)d_in[1];
  const float* w_ih = (const float*)d_in[2];
  const float* w_hh = (const float*)d_in[3];
  const float* b_ih = (const float*)d_in[4];
  const float* b_hh = (const float*)d_in[5];
  float* out = (float*)d_out;

  char* ws = (char*)d_ws;
  u16* A1 = (u16*)ws;                            // 32 MiB
  u16* h3 = (u16*)(ws + 33554432);               // 3 x 128 KiB triple-buffered h
  int* bar = (int*)(ws + 33554432 + 393216);     // 256 epoch flags, 128B stride

  prep_kernel<<<256, 256, 0, stream>>>(h3, bar);
  gather_kernel<<<8192, 256, 0, stream>>>(sent, emb, A1);

  void* args[] = { (void*)&A1, (void*)&w_ih, (void*)&w_hh,
                   (void*)&b_ih, (void*)&b_hh, (void*)&h3, (void*)&out, (void*)&bar };
  hipError_t err = hipLaunchCooperativeKernel((void*)lstm_kernel, dim3(256), dim3(256),
                                              args, 0, stream);
  if (err != hipSuccess) {
    // custom barrier (no cg grid.sync): plain launch is fine when all 256 WGs
    // are co-resident, which the 2-blocks/CU resource envelope guarantees
    lstm_kernel<<<dim3(256), dim3(256), 0, stream>>>(A1, w_ih, w_hh, b_ih, b_hh,
                                                     h3, out, bar);
  }
}